// Round 1
// baseline (425.816 us; speedup 1.0000x reference)
//
#include <hip/hip_runtime.h>
#include <math.h>

#define NCLS 80
#define CH 85

static constexpr int NS = 16 * 76 * 76 * 3;   // 277248 (stride 8)
static constexpr int NM = 16 * 38 * 38 * 3;   //  69312 (stride 16)
static constexpr int NL = 16 * 19 * 19 * 3;   //  17328 (stride 32)
static constexpr int NTOT = NS + NM + NL;     // 363888

__constant__ float c_anchors[18] = {
    12.f, 16.f, 19.f, 36.f, 40.f, 28.f,        // s (stride 8)
    36.f, 75.f, 76.f, 55.f, 72.f, 146.f,       // m (stride 16)
    142.f, 110.f, 192.f, 243.f, 459.f, 401.f   // l (stride 32)
};

__device__ __forceinline__ float fast_rcp(float x) {
    return __builtin_amdgcn_rcpf(x);
}
__device__ __forceinline__ float sigm(float x) {
    return fast_rcp(1.f + __expf(-x));
}

__global__ void init_ws(double* ws) {
    if (threadIdx.x < 3) ws[threadIdx.x] = 0.0;
}

__global__ __launch_bounds__(256) void yolo_main(
    const float* __restrict__ conv_l, const float* __restrict__ conv_m,
    const float* __restrict__ conv_s, const float* __restrict__ lab_s,
    const float* __restrict__ lab_m, const float* __restrict__ lab_l,
    const float* __restrict__ tb, double* __restrict__ ws)
{
    int gid = blockIdx.x * 256 + threadIdx.x;
    float ciou_acc = 0.f, conf_acc = 0.f, prob_acc = 0.f;

    if (gid < NTOT) {
        const float* conv; const float* lab; int S; float stride; int ao;
        int idx = gid;
        if (idx < NS)           { conv = conv_s; lab = lab_s; S = 76; stride = 8.f;  ao = 0;  }
        else if (idx < NS + NM) { idx -= NS;      conv = conv_m; lab = lab_m; S = 38; stride = 16.f; ao = 6;  }
        else                    { idx -= NS + NM; conv = conv_l; lab = lab_l; S = 19; stride = 32.f; ao = 12; }

        int a = idx % 3;
        int t = idx / 3;
        int j = t % S;  t /= S;
        int i = t % S;  int b = t / S;

        const float* cp = conv + (size_t)idx * CH;
        const float* lp = lab  + (size_t)idx * CH;

        float c0 = cp[0], c1 = cp[1], c2v = cp[2], c3 = cp[3], c4 = cp[4];
        float lx = lp[0], ly = lp[1], lw = lp[2], lh = lp[3], resp = lp[4];

        // ---- decode ----
        float px = (sigm(c0) + (float)j) * stride;
        float py = (sigm(c1) + (float)i) * stride;
        float pw = __expf(c2v) * c_anchors[ao + 2 * a];
        float ph = __expf(c3)  * c_anchors[ao + 2 * a + 1];
        float pconf = sigm(c4);

        // ---- CIoU vs label ----
        float hx = 0.5f * pw, hy = 0.5f * ph;
        float b1x1 = px - hx, b1y1 = py - hy, b1x2 = px + hx, b1y2 = py + hy;
        float hlx = 0.5f * lw, hly = 0.5f * lh;
        float b2x1 = lx - hlx, b2y1 = ly - hly, b2x2 = lx + hlx, b2y2 = ly + hly;

        float area1 = (b1x2 - b1x1) * (b1y2 - b1y1);
        float area2 = (b2x2 - b2x1) * (b2y2 - b2y1);
        float lux = fmaxf(b1x1, b2x1), luy = fmaxf(b1y1, b2y1);
        float rdx = fminf(b1x2, b2x2), rdy = fminf(b1y2, b2y2);
        float iw = fmaxf(rdx - lux, 0.f), ih = fmaxf(rdy - luy, 0.f);
        float inter = iw * ih;
        float uni = area1 + area2 - inter;
        float iou = inter / (uni + 1e-9f);

        float encw = fmaxf(b1x2, b2x2) - fminf(b1x1, b2x1);
        float ench = fmaxf(b1y2, b2y2) - fminf(b1y1, b2y1);
        float cc2 = encw * encw + ench * ench;
        float dx = px - lx, dy = py - ly;
        float p2 = dx * dx + dy * dy;
        float at1 = atanf(pw / (ph + 1e-9f));
        float at2 = atanf(lw / (lh + 1e-9f));
        float dat = at1 - at2;
        const float FOUR_OVER_PI2 = 0.40528473456935109f; // 4/pi^2
        float v = FOUR_OVER_PI2 * dat * dat;
        float al = v / (1.f - iou + v);
        float ciou = iou - p2 / cc2 - al * v;
        float bscale = 2.f - lw * lh * (1.f / (608.f * 608.f));
        ciou_acc = resp * bscale * (1.f - ciou);

        // ---- 80-class prob BCE ----
        float pls = 0.f;
        #pragma unroll 4
        for (int k = 0; k < NCLS; k++) {
            float pp  = sigm(cp[5 + k]);
            float lpr = lp[5 + k];
            pls += lpr * (-__logf(pp + 1e-9f)) + (1.f - lpr) * (-__logf(1.f - pp + 1e-9f));
        }
        prob_acc = resp * pls;

        // ---- conf loss: max IoU vs 70 true boxes of batch b ----
        const float* tbp = tb + (size_t)b * 70 * 4;
        float parea = pw * ph;
        float maxiou = 0.f;
        for (int n = 0; n < 70; n++) {
            float tx = tbp[4 * n], ty = tbp[4 * n + 1];
            float tw = tbp[4 * n + 2], th = tbp[4 * n + 3];
            float tx1 = tx - 0.5f * tw, ty1 = ty - 0.5f * th;
            float tx2 = tx + 0.5f * tw, ty2 = ty + 0.5f * th;
            float ix1 = fmaxf(b1x1, tx1), iy1 = fmaxf(b1y1, ty1);
            float ix2 = fminf(b1x2, tx2), iy2 = fminf(b1y2, ty2);
            float iiw = fmaxf(ix2 - ix1, 0.f), iih = fmaxf(iy2 - iy1, 0.f);
            float ia = iiw * iih;
            float u = parea + tw * th - ia;
            maxiou = fmaxf(maxiou, ia * fast_rcp(u));
        }
        float rbgd = (1.f - resp) * (maxiou < 0.5f ? 1.f : 0.f);
        conf_acc = resp * (-__logf(pconf + 1e-9f))
                 + rbgd * (-__logf(1.f - pconf + 1e-9f));
    }

    // ---- block reduce: wave shuffle, then LDS across 4 waves ----
    for (int off = 32; off > 0; off >>= 1) {
        ciou_acc += __shfl_down(ciou_acc, off);
        conf_acc += __shfl_down(conf_acc, off);
        prob_acc += __shfl_down(prob_acc, off);
    }
    __shared__ float red[4][3];
    int lane = threadIdx.x & 63, wv = threadIdx.x >> 6;
    if (lane == 0) { red[wv][0] = ciou_acc; red[wv][1] = conf_acc; red[wv][2] = prob_acc; }
    __syncthreads();
    if (threadIdx.x == 0) {
        float s0 = red[0][0] + red[1][0] + red[2][0] + red[3][0];
        float s1 = red[0][1] + red[1][1] + red[2][1] + red[3][1];
        float s2 = red[0][2] + red[1][2] + red[2][2] + red[3][2];
        atomicAdd(&ws[0], (double)s0);
        atomicAdd(&ws[1], (double)s1);
        atomicAdd(&ws[2], (double)s2);
    }
}

__global__ void finalize_k(const double* __restrict__ ws, float* __restrict__ out) {
    if (threadIdx.x == 0) {
        float ci = (float)(ws[0] / 16.0);
        float co = (float)(ws[1] / 16.0);
        float pr = (float)(ws[2] / 16.0);
        out[0] = ci + co + pr;  // all_loss
        out[1] = ci;            // ciou_loss
        out[2] = co;            // conf_loss
        out[3] = pr;            // prob_loss
    }
}

extern "C" void kernel_launch(void* const* d_in, const int* in_sizes, int n_in,
                              void* d_out, int out_size, void* d_ws, size_t ws_size,
                              hipStream_t stream) {
    const float* conv_l = (const float*)d_in[0];
    const float* conv_m = (const float*)d_in[1];
    const float* conv_s = (const float*)d_in[2];
    const float* lab_s  = (const float*)d_in[3];
    const float* lab_m  = (const float*)d_in[4];
    const float* lab_l  = (const float*)d_in[5];
    const float* tb     = (const float*)d_in[6];
    double* ws = (double*)d_ws;
    float* out = (float*)d_out;

    init_ws<<<1, 64, 0, stream>>>(ws);
    int blocks = (NTOT + 255) / 256;
    yolo_main<<<blocks, 256, 0, stream>>>(conv_l, conv_m, conv_s,
                                          lab_s, lab_m, lab_l, tb, ws);
    finalize_k<<<1, 64, 0, stream>>>(ws, out);
}

// Round 2
// 277.904 us; speedup vs baseline: 1.5322x; 1.5322x over previous
//
#include <hip/hip_runtime.h>
#include <math.h>

#define NCLS 80
#define CH 85

// records per scale
static constexpr int RS = 16 * 76 * 76 * 3;   // 277248 (stride 8)
static constexpr int RM = 16 * 38 * 38 * 3;   //  69312 (stride 16)
static constexpr int RL = 16 * 19 * 19 * 3;   //  17328 (stride 32)

static constexpr int BS_BLK = RS / 256;            // 1083 (exact)
static constexpr int BM_BLK = (RM + 255) / 256;    // 271 (last block 192 recs)
static constexpr int BL_BLK = (RL + 255) / 256;    // 68  (last block 176 recs)
static constexpr int NBLK   = BS_BLK + BM_BLK + BL_BLK;  // 1422

__constant__ float c_anchors[18] = {
    12.f, 16.f, 19.f, 36.f, 40.f, 28.f,        // s (stride 8)
    36.f, 75.f, 76.f, 55.f, 72.f, 146.f,       // m (stride 16)
    142.f, 110.f, 192.f, 243.f, 459.f, 401.f   // l (stride 32)
};

__device__ __forceinline__ float fast_rcp(float x) {
    return __builtin_amdgcn_rcpf(x);
}
__device__ __forceinline__ float sigm(float x) {
    return fast_rcp(1.f + __expf(-x));
}
__device__ __forceinline__ float softplusf(float x) {
    // log(1 + e^x), stable
    return fmaxf(x, 0.f) + __logf(1.f + __expf(-fabsf(x)));
}

__global__ __launch_bounds__(256) void yolo_main(
    const float* __restrict__ conv_l, const float* __restrict__ conv_m,
    const float* __restrict__ conv_s, const float* __restrict__ lab_s,
    const float* __restrict__ lab_m, const float* __restrict__ lab_l,
    const float* __restrict__ tb, float* __restrict__ pb)
{
    int blk = blockIdx.x;

    const float* conv; const float* lab;
    int S; float stride; int ao; int blkLocal; int nrec_scale;
    if (blk < BS_BLK) {
        conv = conv_s; lab = lab_s; S = 76; stride = 8.f;  ao = 0;
        blkLocal = blk;                 nrec_scale = RS;
    } else if (blk < BS_BLK + BM_BLK) {
        conv = conv_m; lab = lab_m; S = 38; stride = 16.f; ao = 6;
        blkLocal = blk - BS_BLK;        nrec_scale = RM;
    } else {
        conv = conv_l; lab = lab_l; S = 19; stride = 32.f; ao = 12;
        blkLocal = blk - BS_BLK - BM_BLK; nrec_scale = RL;
    }

    int r0   = blkLocal * 256;
    int nrec = min(256, nrec_scale - r0);
    int E    = nrec * 85;        // always divisible by 4 (nrec % 4 == 0)
    int n4   = E >> 2;

    const float* cbase = conv + (size_t)r0 * CH;   // 16B-aligned (256*85*4 % 16 == 0)
    const float* lbase = lab  + (size_t)r0 * CH;

    __shared__ float convA[256 * 5];
    __shared__ float labA[256 * 5];

    float ciou_acc = 0.f, conf_acc = 0.f, prob_acc = 0.f;

    // ---- phase 1: coalesced float4 stream, class BCE inline ----
    for (int i4 = threadIdx.x; i4 < n4; i4 += 256) {
        int e = i4 << 2;
        float4 cv = *reinterpret_cast<const float4*>(cbase + e);
        float4 lv = *reinterpret_cast<const float4*>(lbase + e);
        float cvv[4] = {cv.x, cv.y, cv.z, cv.w};
        float lvv[4] = {lv.x, lv.y, lv.z, lv.w};

        unsigned rA  = (unsigned)e / 85u;
        unsigned bnd = (rA + 1u) * 85u;
        float respA = lbase[rA * 85u + 4u];                 // L1 hit (hot line)
        unsigned rB = ((unsigned)(e + 3) >= bnd) ? rA + 1u : rA;
        float respB = lbase[rB * 85u + 4u];

        #pragma unroll
        for (int d = 0; d < 4; d++) {
            unsigned el = (unsigned)(e + d);
            bool nxt   = el >= bnd;
            unsigned r = nxt ? rA + 1u : rA;
            unsigned c = el - r * 85u;
            float x = cvv[d], l = lvv[d];
            if (c >= 5u) {
                float sp = softplusf(x);
                float resp = nxt ? respB : respA;
                prob_acc += resp * (sp - l * x);   // = l*(-log p) + (1-l)*(-log(1-p))
            } else {
                convA[r * 5u + c] = x;
                labA[r * 5u + c]  = l;
            }
        }
    }
    __syncthreads();

    // ---- phase 2: per-record box / conf from LDS ----
    int t = threadIdx.x;
    if (t < nrec) {
        unsigned rl = (unsigned)(r0 + t);
        unsigned a = rl % 3u; unsigned q = rl / 3u;
        unsigned j = q % (unsigned)S; q /= (unsigned)S;
        unsigned i = q % (unsigned)S; unsigned b = q / (unsigned)S;

        float c0 = convA[t * 5 + 0], c1 = convA[t * 5 + 1], c2v = convA[t * 5 + 2];
        float c3 = convA[t * 5 + 3], c4 = convA[t * 5 + 4];
        float lx = labA[t * 5 + 0], ly = labA[t * 5 + 1], lw = labA[t * 5 + 2];
        float lh = labA[t * 5 + 3], resp = labA[t * 5 + 4];

        // decode
        float px = (sigm(c0) + (float)j) * stride;
        float py = (sigm(c1) + (float)i) * stride;
        float pw = __expf(c2v) * c_anchors[ao + 2 * a];
        float ph = __expf(c3)  * c_anchors[ao + 2 * a + 1];

        // CIoU vs label
        float hx = 0.5f * pw, hy = 0.5f * ph;
        float b1x1 = px - hx, b1y1 = py - hy, b1x2 = px + hx, b1y2 = py + hy;
        float hlx = 0.5f * lw, hly = 0.5f * lh;
        float b2x1 = lx - hlx, b2y1 = ly - hly, b2x2 = lx + hlx, b2y2 = ly + hly;

        float area1 = (b1x2 - b1x1) * (b1y2 - b1y1);
        float area2 = (b2x2 - b2x1) * (b2y2 - b2y1);
        float lux = fmaxf(b1x1, b2x1), luy = fmaxf(b1y1, b2y1);
        float rdx = fminf(b1x2, b2x2), rdy = fminf(b1y2, b2y2);
        float iw = fmaxf(rdx - lux, 0.f), ih = fmaxf(rdy - luy, 0.f);
        float inter = iw * ih;
        float uni = area1 + area2 - inter;
        float iou = inter / (uni + 1e-9f);

        float encw = fmaxf(b1x2, b2x2) - fminf(b1x1, b2x1);
        float ench = fmaxf(b1y2, b2y2) - fminf(b1y1, b2y1);
        float cc2 = encw * encw + ench * ench;
        float dx = px - lx, dy = py - ly;
        float p2 = dx * dx + dy * dy;
        float at1 = atanf(pw / (ph + 1e-9f));
        float at2 = atanf(lw / (lh + 1e-9f));
        float dat = at1 - at2;
        const float FOUR_OVER_PI2 = 0.40528473456935109f;  // 4/pi^2
        float v = FOUR_OVER_PI2 * dat * dat;
        float al = v / (1.f - iou + v);
        float ciou = iou - p2 / cc2 - al * v;
        float bscale = 2.f - lw * lh * (1.f / (608.f * 608.f));
        ciou_acc = resp * bscale * (1.f - ciou);

        // conf loss: max IoU vs 70 true boxes of batch b
        const float* tbp = tb + (size_t)b * 70 * 4;
        float parea = pw * ph;
        float maxiou = 0.f;
        for (int n = 0; n < 70; n++) {
            float tx = tbp[4 * n], ty = tbp[4 * n + 1];
            float tw = tbp[4 * n + 2], th = tbp[4 * n + 3];
            float tx1 = tx - 0.5f * tw, ty1 = ty - 0.5f * th;
            float tx2 = tx + 0.5f * tw, ty2 = ty + 0.5f * th;
            float ix1 = fmaxf(b1x1, tx1), iy1 = fmaxf(b1y1, ty1);
            float ix2 = fminf(b1x2, tx2), iy2 = fminf(b1y2, ty2);
            float iiw = fmaxf(ix2 - ix1, 0.f), iih = fmaxf(iy2 - iy1, 0.f);
            float ia = iiw * iih;
            float u = parea + tw * th - ia;
            maxiou = fmaxf(maxiou, ia * fast_rcp(u));
        }
        float rbgd = (1.f - resp) * (maxiou < 0.5f ? 1.f : 0.f);
        // -log(sigm(x)+eps) ~= softplus(x)-x ; -log(1-sigm(x)+eps) ~= softplus(x)
        float spc = softplusf(c4);
        conf_acc = resp * (spc - c4) + rbgd * spc;
    }

    // ---- block reduce → per-block partials ----
    for (int off = 32; off > 0; off >>= 1) {
        ciou_acc += __shfl_down(ciou_acc, off);
        conf_acc += __shfl_down(conf_acc, off);
        prob_acc += __shfl_down(prob_acc, off);
    }
    __shared__ float red[4][3];
    int lane = threadIdx.x & 63, wv = threadIdx.x >> 6;
    if (lane == 0) { red[wv][0] = ciou_acc; red[wv][1] = conf_acc; red[wv][2] = prob_acc; }
    __syncthreads();
    if (threadIdx.x == 0) {
        pb[blk]            = red[0][0] + red[1][0] + red[2][0] + red[3][0];
        pb[NBLK + blk]     = red[0][1] + red[1][1] + red[2][1] + red[3][1];
        pb[2 * NBLK + blk] = red[0][2] + red[1][2] + red[2][2] + red[3][2];
    }
}

__global__ __launch_bounds__(256) void finalize_k(const float* __restrict__ pb,
                                                  float* __restrict__ out)
{
    double s0 = 0.0, s1 = 0.0, s2 = 0.0;
    for (int i = threadIdx.x; i < NBLK; i += 256) {
        s0 += (double)pb[i];
        s1 += (double)pb[NBLK + i];
        s2 += (double)pb[2 * NBLK + i];
    }
    for (int off = 32; off > 0; off >>= 1) {
        s0 += __shfl_down(s0, off);
        s1 += __shfl_down(s1, off);
        s2 += __shfl_down(s2, off);
    }
    __shared__ double rd[4][3];
    int lane = threadIdx.x & 63, wv = threadIdx.x >> 6;
    if (lane == 0) { rd[wv][0] = s0; rd[wv][1] = s1; rd[wv][2] = s2; }
    __syncthreads();
    if (threadIdx.x == 0) {
        float ci = (float)((rd[0][0] + rd[1][0] + rd[2][0] + rd[3][0]) / 16.0);
        float co = (float)((rd[0][1] + rd[1][1] + rd[2][1] + rd[3][1]) / 16.0);
        float pr = (float)((rd[0][2] + rd[1][2] + rd[2][2] + rd[3][2]) / 16.0);
        out[0] = ci + co + pr;
        out[1] = ci;
        out[2] = co;
        out[3] = pr;
    }
}

extern "C" void kernel_launch(void* const* d_in, const int* in_sizes, int n_in,
                              void* d_out, int out_size, void* d_ws, size_t ws_size,
                              hipStream_t stream) {
    const float* conv_l = (const float*)d_in[0];
    const float* conv_m = (const float*)d_in[1];
    const float* conv_s = (const float*)d_in[2];
    const float* lab_s  = (const float*)d_in[3];
    const float* lab_m  = (const float*)d_in[4];
    const float* lab_l  = (const float*)d_in[5];
    const float* tb     = (const float*)d_in[6];
    float* pb  = (float*)d_ws;   // 3*NBLK floats of partials
    float* out = (float*)d_out;

    yolo_main<<<NBLK, 256, 0, stream>>>(conv_l, conv_m, conv_s,
                                        lab_s, lab_m, lab_l, tb, pb);
    finalize_k<<<1, 256, 0, stream>>>(pb, out);
}